// Round 2
// baseline (198.304 us; speedup 1.0000x reference)
//
#include <hip/hip_runtime.h>

#define BB 8
#define NN 8192
#define SS 2048
#define CC 64
#define NS 32
#define COUT 67   // 3 xyz + 64 feature channels
#define QT 8      // queries per gather block
#define P0 19     // planes in quad 0 (3 xyz + 16 feat); quads 1..3 have 16

typedef float f32x4 __attribute__((ext_vector_type(4)));

// ---------------- Kernel A: ball-query scan, float4-vectorized loads --------
// Lane owns 4 consecutive points: j = j0 + 4*lane + u. 3x dwordx4 per chunk,
// each a coalesced 1KB wave fetch. Hit ordering is lane-major.
__global__ __launch_bounds__(256) void scan_kernel(
    const float* __restrict__ xyz,      // (B, N, 3)
    const float* __restrict__ new_xyz,  // (B, S, 3)
    int* __restrict__ idx_ws)           // (B*S, NS)
{
#pragma clang fp contract(off)
    const int wave = threadIdx.x >> 6;
    const int lane = threadIdx.x & 63;
    const int qid  = blockIdx.x * 4 + wave;
    const int b = qid >> 11;
    const int s = qid & 2047;

    const float R2 = 0.04f;   // f32 nearest of 0.2*0.2; strict '<' matches ref

    const float* ctr = new_xyz + ((size_t)b * SS + s) * 3;
    const float cx = ctr[0], cy = ctr[1], cz = ctr[2];
    const float* xb = xyz + (size_t)b * NN * 3;

    int* myidx = idx_ws + (size_t)qid * NS;
    const unsigned long long lt = (1ull << lane) - 1ull;

    int total = 0;
    int firstIdx = -1;
    for (int j0 = 0; j0 < NN && total < NS; j0 += 256) {
        // 48B-aligned: (j0 + 4*lane)*12 bytes is a multiple of 48
        const float4* p4 = (const float4*)(xb + (size_t)(j0 + (lane << 2)) * 3);
        const float4 A  = p4[0];   // x0 y0 z0 x1
        const float4 Bv = p4[1];   // y1 z1 x2 y2
        const float4 Cv = p4[2];   // z2 x3 y3 z3
        float d2v[4];
        {
            const float dx = A.x - cx, dy = A.y - cy, dz = A.z - cz;
            float d2 = dx * dx; d2 = d2 + dy * dy; d2 = d2 + dz * dz;
            d2v[0] = d2;
        }
        {
            const float dx = A.w - cx, dy = Bv.x - cy, dz = Bv.y - cz;
            float d2 = dx * dx; d2 = d2 + dy * dy; d2 = d2 + dz * dz;
            d2v[1] = d2;
        }
        {
            const float dx = Bv.z - cx, dy = Bv.w - cy, dz = Cv.x - cz;
            float d2 = dx * dx; d2 = d2 + dy * dy; d2 = d2 + dz * dz;
            d2v[2] = d2;
        }
        {
            const float dx = Cv.y - cx, dy = Cv.z - cy, dz = Cv.w - cz;
            float d2 = dx * dx; d2 = d2 + dy * dy; d2 = d2 + dz * dz;
            d2v[3] = d2;
        }

        unsigned long long M[4];
#pragma unroll
        for (int u = 0; u < 4; ++u) M[u] = __ballot(d2v[u] < R2);

        if (firstIdx < 0) {
            int fmin = 0x7fffffff;
#pragma unroll
            for (int u = 0; u < 4; ++u)
                if (M[u] != 0ull) {
                    const int j = j0 + (__builtin_ctzll(M[u]) << 2) + u;
                    fmin = (j < fmin) ? j : fmin;
                }
            if (fmin != 0x7fffffff) firstIdx = fmin;
        }

        int below = 0;   // hits in earlier lanes (any u) -> smaller j
#pragma unroll
        for (int u = 0; u < 4; ++u) below += (int)__popcll(M[u] & lt);

        int own = 0;     // own hits with smaller u -> smaller j
#pragma unroll
        for (int u = 0; u < 4; ++u) {
            if (d2v[u] < R2) {
                const int pos = total + below + own;
                if (pos < NS) myidx[pos] = j0 + (lane << 2) + u;
                ++own;
            }
        }
#pragma unroll
        for (int u = 0; u < 4; ++u) total += (int)__popcll(M[u]);
    }
    if (total < NS) {
        const int fill = (total > 0) ? firstIdx : 0;
        if (lane >= total && lane < NS) myidx[lane] = fill;
    }
}

// ---------------- Kernel B: gather, XCD-affine + nontemporal writes ---------
// Flat 8192-block grid decoded b-fastest: b = bid & 7. Round-robin dispatch
// puts all blocks of batch k on XCD k -> per-XCD L2 working set is ONE batch
// (2 MB feat + idx + xyz), pure L2 hits on the scattered reads. Output is
// write-once: nontemporal stores keep the 140 MB stream from thrashing L2.
// quad next-fastest so a row's four 64B quarters hit the same L2 lines.
__global__ __launch_bounds__(256) void gather_kernel(
    const float* __restrict__ xyz,      // (B, N, 3)
    const float* __restrict__ new_xyz,  // (B, S, 3)
    const float* __restrict__ feat,     // (B, N, C)
    const int* __restrict__ idx_ws,     // (B*S, NS)
    float* __restrict__ out)            // (B, 67, S, NS)
{
#pragma clang fp contract(off)
    __shared__ float tile[P0 * QT * NS];    // 19 * 256 floats = 19 KB
    __shared__ int idx_sh[QT * NS];         // 1 KB

    const int t   = threadIdx.x;            // = q*32 + k
    const int bid = blockIdx.x;             // 0..8191, b-fastest layout
    const int b     = bid & 7;              // XCD-affine: bid%8 ~ XCD id
    const int rem   = bid >> 3;
    const int quad  = rem & 3;              // 4 quads of one sTile adjacent
    const int sTile = rem >> 2;             // 0..255

    const int s0 = sTile * QT;
    const int qbase = (b << 11) + s0;

    idx_sh[t] = idx_ws[(size_t)qbase * NS + t];
    __syncthreads();

    const int q = t >> 5;
    const int row = idx_sh[t];

    // ---- read phase: fill LDS tile [plane][q*32+k] ----
    const float* frow = feat + ((size_t)b * NN + row) * CC + quad * 16;
    const int pb = (quad == 0) ? 3 : 0;
    if (quad == 0) {
        const float* ctr = new_xyz + ((size_t)b * SS + s0 + q) * 3;
        const float* p   = xyz + ((size_t)b * NN + row) * 3;
        tile[0 * 256 + t] = p[0] - ctr[0];
        tile[1 * 256 + t] = p[1] - ctr[1];
        tile[2 * 256 + t] = p[2] - ctr[2];
    }
#pragma unroll
    for (int i = 0; i < 4; ++i) {
        const float4 f = *(const float4*)(frow + i * 4);
        tile[(pb + i * 4 + 0) * 256 + t] = f.x;
        tile[(pb + i * 4 + 1) * 256 + t] = f.y;
        tile[(pb + i * 4 + 2) * 256 + t] = f.z;
        tile[(pb + i * 4 + 3) * 256 + t] = f.w;
    }
    __syncthreads();

    // ---- write phase: one 1KB-contiguous nontemporal wave-store per plane --
    const int P     = (quad == 0) ? P0 : 16;              // planes this block owns
    const int cbase = (quad == 0) ? 0 : (3 + quad * 16);  // global channel base
    const int wv = t >> 6;
    const int ln = t & 63;
    const size_t plane = (size_t)SS * NS;
    float* ob = out + (((size_t)b * COUT + cbase) * SS + s0) * NS;
#pragma unroll
    for (int i = 0; i < 5; ++i) {
        const int p = i * 4 + wv;
        if (p < P) {
            const f32x4 v = *(const f32x4*)(tile + p * 256 + ln * 4);
            __builtin_nontemporal_store(v, (f32x4*)(ob + (size_t)p * plane + ln * 4));
        }
    }
}

extern "C" void kernel_launch(void* const* d_in, const int* in_sizes, int n_in,
                              void* d_out, int out_size, void* d_ws, size_t ws_size,
                              hipStream_t stream) {
    const float* xyz     = (const float*)d_in[0];
    const float* new_xyz = (const float*)d_in[1];
    const float* feat    = (const float*)d_in[2];
    float* out = (float*)d_out;
    int* idx_ws = (int*)d_ws;   // B*S*NS ints = 2 MB

    scan_kernel<<<dim3((BB * SS) / 4), dim3(256), 0, stream>>>(xyz, new_xyz, idx_ws);
    gather_kernel<<<dim3(SS / QT * 4 * BB), dim3(256), 0, stream>>>(xyz, new_xyz, feat, idx_ws, out);
}

// Round 3
// 186.800 us; speedup vs baseline: 1.0616x; 1.0616x over previous
//
#include <hip/hip_runtime.h>

#define BB 8
#define NN 8192
#define SS 2048
#define CC 64
#define NS 32
#define COUT 67        // 3 xyz + 64 feature channels
#define QT 4           // queries per gather block
#define SLOTS (QT*NS)  // 128 (query,sample) slots per block
#define FSTR 65        // padded LDS stride: write free, transpose-read 2-way

typedef float f32x4 __attribute__((ext_vector_type(4)));

// ---------------- Kernel A: ball-query scan (verified bit-exact) ------------
// Lane owns 4 consecutive points: j = j0 + 4*lane + u. 3x dwordx4 per chunk,
// each a coalesced 1KB wave fetch. Hit ordering is lane-major.
__global__ __launch_bounds__(256) void scan_kernel(
    const float* __restrict__ xyz,      // (B, N, 3)
    const float* __restrict__ new_xyz,  // (B, S, 3)
    int* __restrict__ idx_ws)           // (B*S, NS)
{
#pragma clang fp contract(off)
    const int wave = threadIdx.x >> 6;
    const int lane = threadIdx.x & 63;
    const int qid  = blockIdx.x * 4 + wave;
    const int b = qid >> 11;
    const int s = qid & 2047;

    const float R2 = 0.04f;   // f32 nearest of 0.2*0.2; strict '<' matches ref

    const float* ctr = new_xyz + ((size_t)b * SS + s) * 3;
    const float cx = ctr[0], cy = ctr[1], cz = ctr[2];
    const float* xb = xyz + (size_t)b * NN * 3;

    int* myidx = idx_ws + (size_t)qid * NS;
    const unsigned long long lt = (1ull << lane) - 1ull;

    int total = 0;
    int firstIdx = -1;
    for (int j0 = 0; j0 < NN && total < NS; j0 += 256) {
        // 48B-aligned: (j0 + 4*lane)*12 bytes is a multiple of 48
        const float4* p4 = (const float4*)(xb + (size_t)(j0 + (lane << 2)) * 3);
        const float4 A  = p4[0];   // x0 y0 z0 x1
        const float4 Bv = p4[1];   // y1 z1 x2 y2
        const float4 Cv = p4[2];   // z2 x3 y3 z3
        float d2v[4];
        {
            const float dx = A.x - cx, dy = A.y - cy, dz = A.z - cz;
            float d2 = dx * dx; d2 = d2 + dy * dy; d2 = d2 + dz * dz;
            d2v[0] = d2;
        }
        {
            const float dx = A.w - cx, dy = Bv.x - cy, dz = Bv.y - cz;
            float d2 = dx * dx; d2 = d2 + dy * dy; d2 = d2 + dz * dz;
            d2v[1] = d2;
        }
        {
            const float dx = Bv.z - cx, dy = Bv.w - cy, dz = Cv.x - cz;
            float d2 = dx * dx; d2 = d2 + dy * dy; d2 = d2 + dz * dz;
            d2v[2] = d2;
        }
        {
            const float dx = Cv.y - cx, dy = Cv.z - cy, dz = Cv.w - cz;
            float d2 = dx * dx; d2 = d2 + dy * dy; d2 = d2 + dz * dz;
            d2v[3] = d2;
        }

        unsigned long long M[4];
#pragma unroll
        for (int u = 0; u < 4; ++u) M[u] = __ballot(d2v[u] < R2);

        if (firstIdx < 0) {
            int fmin = 0x7fffffff;
#pragma unroll
            for (int u = 0; u < 4; ++u)
                if (M[u] != 0ull) {
                    const int j = j0 + (__builtin_ctzll(M[u]) << 2) + u;
                    fmin = (j < fmin) ? j : fmin;
                }
            if (fmin != 0x7fffffff) firstIdx = fmin;
        }

        int below = 0;   // hits in earlier lanes (any u) -> smaller j
#pragma unroll
        for (int u = 0; u < 4; ++u) below += (int)__popcll(M[u] & lt);

        int own = 0;     // own hits with smaller u -> smaller j
#pragma unroll
        for (int u = 0; u < 4; ++u) {
            if (d2v[u] < R2) {
                const int pos = total + below + own;
                if (pos < NS) myidx[pos] = j0 + (lane << 2) + u;
                ++own;
            }
        }
#pragma unroll
        for (int u = 0; u < 4; ++u) total += (int)__popcll(M[u]);
    }
    if (total < NS) {
        const int fill = (total > 0) ? firstIdx : 0;
        if (lane >= total && lane < NS) myidx[lane] = fill;
    }
}

// ---------------- Kernel B: gather, wave-coalesced row reads ----------------
// One feature row = 64 floats = one dword per lane: each slot's row is read by
// a full wave as ONE coalesced 256B load (4 cache lines/instr, was 64).
// LDS stage untransposed ft[slot][chan], stride 65: chan-major writes are
// bank-free, plane-major transpose reads are 2-way (free). Output planes
// stream as contiguous 256B nontemporal wave-stores.
__global__ __launch_bounds__(256) void gather_kernel(
    const float* __restrict__ xyz,      // (B, N, 3)
    const float* __restrict__ new_xyz,  // (B, S, 3)
    const float* __restrict__ feat,     // (B, N, C)
    const int* __restrict__ idx_ws,     // (B*S, NS)
    float* __restrict__ out)            // (B, 67, S, NS)
{
#pragma clang fp contract(off)
    __shared__ float ft[SLOTS * FSTR];   // 128*65*4B = 33.3 KB
    __shared__ float xt[3 * SLOTS];      // 1.5 KB, [plane][slot]
    __shared__ int idx_sh[SLOTS];        // 0.5 KB

    const int t   = threadIdx.x;
    const int bid = blockIdx.x;          // 0..4095, b-fastest
    const int b     = bid & 7;
    const int sTile = bid >> 3;          // 0..511
    const int s0 = sTile * QT;
    const int qbase = (b << 11) + s0;

    if (t < SLOTS) idx_sh[t] = idx_ws[(size_t)qbase * NS + t];
    __syncthreads();

    // ---- xyz planes: one slot per thread (small, divergent but tiny) ----
    if (t < SLOTS) {
        const int r = idx_sh[t];
        const int q = t >> 5;
        const float* ctr = new_xyz + ((size_t)b * SS + s0 + q) * 3;
        const float* p   = xyz + ((size_t)b * NN + r) * 3;
        xt[0 * SLOTS + t] = p[0] - ctr[0];
        xt[1 * SLOTS + t] = p[1] - ctr[1];
        xt[2 * SLOTS + t] = p[2] - ctr[2];
    }

    // ---- cooperative feat reads: wave w covers slots 32w..32w+31 ----
    const int w  = t >> 6;
    const int ln = t & 63;
    const float* fb = feat + (size_t)b * NN * CC;
    for (int i = 0; i < 32; i += 4) {
        float v[4];
        int   mm[4];
#pragma unroll
        for (int u = 0; u < 4; ++u) {
            const int m = (w << 5) + i + u;
            mm[u] = m;
            v[u]  = fb[(size_t)idx_sh[m] * CC + ln];   // 256B coalesced
        }
#pragma unroll
        for (int u = 0; u < 4; ++u)
            ft[mm[u] * FSTR + ln] = v[u];              // bank-free
    }
    __syncthreads();

    // ---- write-out: 134 tasks = 67 planes x 2 half-runs of 64 floats ----
    const size_t plane = (size_t)SS * NS;
    float* ob = out + ((size_t)b * COUT * SS + s0) * NS;
    for (int i = 0; i < 34; ++i) {
        const int tau = (i << 2) + w;
        if (tau < 134) {
            const int p  = tau >> 1;
            const int j  = tau & 1;
            const int sl = (j << 6) + ln;
            const float val = (p < 3) ? xt[p * SLOTS + sl]
                                      : ft[sl * FSTR + (p - 3)];  // 2-way, free
            __builtin_nontemporal_store(val, ob + (size_t)p * plane + sl);
        }
    }
}

extern "C" void kernel_launch(void* const* d_in, const int* in_sizes, int n_in,
                              void* d_out, int out_size, void* d_ws, size_t ws_size,
                              hipStream_t stream) {
    const float* xyz     = (const float*)d_in[0];
    const float* new_xyz = (const float*)d_in[1];
    const float* feat    = (const float*)d_in[2];
    float* out = (float*)d_out;
    int* idx_ws = (int*)d_ws;   // B*S*NS ints = 2 MB

    scan_kernel<<<dim3((BB * SS) / 4), dim3(256), 0, stream>>>(xyz, new_xyz, idx_ws);
    gather_kernel<<<dim3((BB * SS) / QT), dim3(256), 0, stream>>>(xyz, new_xyz, feat, idx_ws, out);
}

// Round 4
// 179.131 us; speedup vs baseline: 1.1070x; 1.0428x over previous
//
#include <hip/hip_runtime.h>

#define BB 8
#define NN 8192
#define SS 2048
#define CC 64
#define NS 32
#define COUT 67        // 3 xyz + 64 feature channels
#define QT 4           // queries per block (one scan-wave each)
#define SLOTS (QT*NS)  // 128 (query,sample) slots per block
#define FSTR 65        // padded LDS stride: write free, transpose-read 2-way

// ---------------- Fused kernel: scan (wave-per-query) + gather --------------
// Phase 1: wave w ball-queries s0+w, writing its 32 indices to LDS (exact
// same arithmetic/ordering as the verified standalone scan). Phase 2: R3's
// gather body (wave-coalesced 256B row reads, LDS transpose, contiguous
// plane stores) -- now through L2 (NT removed: R1->R2 A/B showed NT cost
// ~+5us; L2 write-combining turns 256B bursts into full-line writebacks).
__global__ __launch_bounds__(256) void fused_kernel(
    const float* __restrict__ xyz,      // (B, N, 3)
    const float* __restrict__ new_xyz,  // (B, S, 3)
    const float* __restrict__ feat,     // (B, N, C)
    float* __restrict__ out)            // (B, 67, S, NS)
{
#pragma clang fp contract(off)
    __shared__ float ft[SLOTS * FSTR];   // 128*65*4B = 33.3 KB
    __shared__ float xt[3 * SLOTS];      // 1.5 KB, [plane][slot]
    __shared__ int idx_sh[SLOTS];        // 0.5 KB

    const int t   = threadIdx.x;
    const int w   = t >> 6;              // wave 0..3
    const int ln  = t & 63;
    const int bid = blockIdx.x;          // 0..4095, b-fastest (XCD-affine)
    const int b     = bid & 7;
    const int sTile = bid >> 3;          // 0..511
    const int s0 = sTile * QT;

    // ================= Phase 1: ball-query scan (bit-exact) =================
    {
        const int s = s0 + w;
        const float R2 = 0.04f;          // strict '<' matches ref

        const float* ctr = new_xyz + ((size_t)b * SS + s) * 3;
        const float cx = ctr[0], cy = ctr[1], cz = ctr[2];
        const float* xb = xyz + (size_t)b * NN * 3;

        int* myidx = idx_sh + (w << 5);
        const unsigned long long lt = (1ull << ln) - 1ull;

        int total = 0;
        int firstIdx = -1;
        for (int j0 = 0; j0 < NN && total < NS; j0 += 256) {
            // 48B-aligned: (j0 + 4*ln)*12 bytes is a multiple of 48
            const float4* p4 = (const float4*)(xb + (size_t)(j0 + (ln << 2)) * 3);
            const float4 A  = p4[0];   // x0 y0 z0 x1
            const float4 Bv = p4[1];   // y1 z1 x2 y2
            const float4 Cv = p4[2];   // z2 x3 y3 z3
            float d2v[4];
            {
                const float dx = A.x - cx, dy = A.y - cy, dz = A.z - cz;
                float d2 = dx * dx; d2 = d2 + dy * dy; d2 = d2 + dz * dz;
                d2v[0] = d2;
            }
            {
                const float dx = A.w - cx, dy = Bv.x - cy, dz = Bv.y - cz;
                float d2 = dx * dx; d2 = d2 + dy * dy; d2 = d2 + dz * dz;
                d2v[1] = d2;
            }
            {
                const float dx = Bv.z - cx, dy = Bv.w - cy, dz = Cv.x - cz;
                float d2 = dx * dx; d2 = d2 + dy * dy; d2 = d2 + dz * dz;
                d2v[2] = d2;
            }
            {
                const float dx = Cv.y - cx, dy = Cv.z - cy, dz = Cv.w - cz;
                float d2 = dx * dx; d2 = d2 + dy * dy; d2 = d2 + dz * dz;
                d2v[3] = d2;
            }

            unsigned long long M[4];
#pragma unroll
            for (int u = 0; u < 4; ++u) M[u] = __ballot(d2v[u] < R2);

            if (firstIdx < 0) {
                int fmin = 0x7fffffff;
#pragma unroll
                for (int u = 0; u < 4; ++u)
                    if (M[u] != 0ull) {
                        const int j = j0 + (__builtin_ctzll(M[u]) << 2) + u;
                        fmin = (j < fmin) ? j : fmin;
                    }
                if (fmin != 0x7fffffff) firstIdx = fmin;
            }

            int below = 0;   // hits in earlier lanes (any u) -> smaller j
#pragma unroll
            for (int u = 0; u < 4; ++u) below += (int)__popcll(M[u] & lt);

            int own = 0;     // own hits with smaller u -> smaller j
#pragma unroll
            for (int u = 0; u < 4; ++u) {
                if (d2v[u] < R2) {
                    const int pos = total + below + own;
                    if (pos < NS) myidx[pos] = j0 + (ln << 2) + u;
                    ++own;
                }
            }
#pragma unroll
            for (int u = 0; u < 4; ++u) total += (int)__popcll(M[u]);
        }
        if (total < NS) {
            const int fill = (total > 0) ? firstIdx : 0;
            if (ln >= total && ln < NS) myidx[ln] = fill;
        }
    }
    __syncthreads();

    // ================= Phase 2: gather (R3 structure, no NT) ================
    // ---- xyz planes: one slot per thread (small, divergent but tiny) ----
    if (t < SLOTS) {
        const int r = idx_sh[t];
        const int q = t >> 5;
        const float* ctr = new_xyz + ((size_t)b * SS + s0 + q) * 3;
        const float* p   = xyz + ((size_t)b * NN + r) * 3;
        xt[0 * SLOTS + t] = p[0] - ctr[0];
        xt[1 * SLOTS + t] = p[1] - ctr[1];
        xt[2 * SLOTS + t] = p[2] - ctr[2];
    }

    // ---- cooperative feat reads: wave w covers slots 32w..32w+31 ----
    // One feature row = 64 floats = one dword per lane: ONE coalesced 256B
    // wave-load per slot (4 cache lines/instr).
    const float* fb = feat + (size_t)b * NN * CC;
    for (int i = 0; i < 32; i += 4) {
        float v[4];
        int   mm[4];
#pragma unroll
        for (int u = 0; u < 4; ++u) {
            const int m = (w << 5) + i + u;
            mm[u] = m;
            v[u]  = fb[(size_t)idx_sh[m] * CC + ln];   // 256B coalesced
        }
#pragma unroll
        for (int u = 0; u < 4; ++u)
            ft[mm[u] * FSTR + ln] = v[u];              // bank-free
    }
    __syncthreads();

    // ---- write-out: 134 tasks = 67 planes x 2 half-runs of 64 floats ----
    // Normal (L2-cached) stores: adjacent blocks' runs combine to full lines.
    const size_t plane = (size_t)SS * NS;
    float* ob = out + ((size_t)b * COUT * SS + s0) * NS;
    for (int i = 0; i < 34; ++i) {
        const int tau = (i << 2) + w;
        if (tau < 134) {
            const int p  = tau >> 1;
            const int j  = tau & 1;
            const int sl = (j << 6) + ln;
            const float val = (p < 3) ? xt[p * SLOTS + sl]
                                      : ft[sl * FSTR + (p - 3)];  // 2-way, free
            ob[(size_t)p * plane + sl] = val;
        }
    }
}

extern "C" void kernel_launch(void* const* d_in, const int* in_sizes, int n_in,
                              void* d_out, int out_size, void* d_ws, size_t ws_size,
                              hipStream_t stream) {
    const float* xyz     = (const float*)d_in[0];
    const float* new_xyz = (const float*)d_in[1];
    const float* feat    = (const float*)d_in[2];
    float* out = (float*)d_out;
    (void)d_ws; (void)ws_size;   // idx lives in LDS now

    fused_kernel<<<dim3((BB * SS) / QT), dim3(256), 0, stream>>>(xyz, new_xyz, feat, out);
}

// Round 5
// 176.859 us; speedup vs baseline: 1.1213x; 1.0128x over previous
//
#include <hip/hip_runtime.h>

#define BB 8
#define NN 8192
#define SS 2048
#define CC 64
#define NS 32
#define COUT 67        // 3 xyz + 64 feature channels
#define QT 4           // queries per block (one scan-wave each)
#define SLOTS (QT*NS)  // 128 (query,sample) slots per block
#define HSTR 33        // half-tile LDS stride: write free, transpose-read 2-way

// ---------------- Fused kernel: scan (wave-per-query) + gather --------------
// Phase 1: wave w ball-queries s0+w into LDS (bit-exact verified scan).
// Phase 2: gather with HALF-channel staging: fh[128][33] = 16.5 KB instead of
// 33.3 KB -> total LDS 18.5 KB -> 6 blocks/CU (launch_bounds cap) vs 4.
// +50% resident waves hides (a) intra-block scan imbalance (E[max of 4
// early-exit waves] ~ 2x mean) and (b) the per-chunk load->ballot latency
// chain. Wave-loads stay 256B-coalesced: 2 rows x 32 channels per instr.
__global__ __launch_bounds__(256, 6) void fused_kernel(
    const float* __restrict__ xyz,      // (B, N, 3)
    const float* __restrict__ new_xyz,  // (B, S, 3)
    const float* __restrict__ feat,     // (B, N, C)
    float* __restrict__ out)            // (B, 67, S, NS)
{
#pragma clang fp contract(off)
    __shared__ float fh[SLOTS * HSTR];   // 128*33*4B = 16.5 KB (half channels)
    __shared__ float xt[3 * SLOTS];      // 1.5 KB, [plane][slot]
    __shared__ int idx_sh[SLOTS];        // 0.5 KB

    const int t   = threadIdx.x;
    const int w   = t >> 6;              // wave 0..3
    const int ln  = t & 63;
    const int bid = blockIdx.x;          // 0..4095, b-fastest (XCD-affine)
    const int b     = bid & 7;
    const int sTile = bid >> 3;          // 0..511
    const int s0 = sTile * QT;

    // ================= Phase 1: ball-query scan (bit-exact) =================
    {
        const int s = s0 + w;
        const float R2 = 0.04f;          // strict '<' matches ref

        const float* ctr = new_xyz + ((size_t)b * SS + s) * 3;
        const float cx = ctr[0], cy = ctr[1], cz = ctr[2];
        const float* xb = xyz + (size_t)b * NN * 3;

        int* myidx = idx_sh + (w << 5);
        const unsigned long long lt = (1ull << ln) - 1ull;

        int total = 0;
        int firstIdx = -1;
        for (int j0 = 0; j0 < NN && total < NS; j0 += 256) {
            // 48B-aligned: (j0 + 4*ln)*12 bytes is a multiple of 48
            const float4* p4 = (const float4*)(xb + (size_t)(j0 + (ln << 2)) * 3);
            const float4 A  = p4[0];   // x0 y0 z0 x1
            const float4 Bv = p4[1];   // y1 z1 x2 y2
            const float4 Cv = p4[2];   // z2 x3 y3 z3
            float d2v[4];
            {
                const float dx = A.x - cx, dy = A.y - cy, dz = A.z - cz;
                float d2 = dx * dx; d2 = d2 + dy * dy; d2 = d2 + dz * dz;
                d2v[0] = d2;
            }
            {
                const float dx = A.w - cx, dy = Bv.x - cy, dz = Bv.y - cz;
                float d2 = dx * dx; d2 = d2 + dy * dy; d2 = d2 + dz * dz;
                d2v[1] = d2;
            }
            {
                const float dx = Bv.z - cx, dy = Bv.w - cy, dz = Cv.x - cz;
                float d2 = dx * dx; d2 = d2 + dy * dy; d2 = d2 + dz * dz;
                d2v[2] = d2;
            }
            {
                const float dx = Cv.y - cx, dy = Cv.z - cy, dz = Cv.w - cz;
                float d2 = dx * dx; d2 = d2 + dy * dy; d2 = d2 + dz * dz;
                d2v[3] = d2;
            }

            unsigned long long M[4];
#pragma unroll
            for (int u = 0; u < 4; ++u) M[u] = __ballot(d2v[u] < R2);

            if (firstIdx < 0) {
                int fmin = 0x7fffffff;
#pragma unroll
                for (int u = 0; u < 4; ++u)
                    if (M[u] != 0ull) {
                        const int j = j0 + (__builtin_ctzll(M[u]) << 2) + u;
                        fmin = (j < fmin) ? j : fmin;
                    }
                if (fmin != 0x7fffffff) firstIdx = fmin;
            }

            int below = 0;   // hits in earlier lanes (any u) -> smaller j
#pragma unroll
            for (int u = 0; u < 4; ++u) below += (int)__popcll(M[u] & lt);

            int own = 0;     // own hits with smaller u -> smaller j
#pragma unroll
            for (int u = 0; u < 4; ++u) {
                if (d2v[u] < R2) {
                    const int pos = total + below + own;
                    if (pos < NS) myidx[pos] = j0 + (ln << 2) + u;
                    ++own;
                }
            }
#pragma unroll
            for (int u = 0; u < 4; ++u) total += (int)__popcll(M[u]);
        }
        if (total < NS) {
            const int fill = (total > 0) ? firstIdx : 0;
            if (ln >= total && ln < NS) myidx[ln] = fill;
        }
    }
    __syncthreads();

    // ================= Phase 2: gather, half-channel staged =================
    // ---- xyz planes: one slot per thread (small, divergent but tiny) ----
    if (t < SLOTS) {
        const int r = idx_sh[t];
        const int q = t >> 5;
        const float* ctr = new_xyz + ((size_t)b * SS + s0 + q) * 3;
        const float* p   = xyz + ((size_t)b * NN + r) * 3;
        xt[0 * SLOTS + t] = p[0] - ctr[0];
        xt[1 * SLOTS + t] = p[1] - ctr[1];
        xt[2 * SLOTS + t] = p[2] - ctr[2];
    }

    const int c32 = ln & 31;             // channel within half
    const int sub = ln >> 5;             // which of 2 rows this lane covers
    const float* fb = feat + (size_t)b * NN * CC;
    const size_t plane = (size_t)SS * NS;
    float* ob = out + ((size_t)b * COUT * SS + s0) * NS;

    // ---- stage half 0: channels 0..31 for all 128 slots ----
    // wave w covers slots 32w..32w+31; one wave-load = 2 rows x 128B.
    for (int i = 0; i < 16; i += 4) {
        float v[4];
        int   mm[4];
#pragma unroll
        for (int u = 0; u < 4; ++u) {
            const int m = (w << 5) + ((i + u) << 1) + sub;
            mm[u] = m;
            v[u]  = fb[(size_t)idx_sh[m] * CC + c32];
        }
#pragma unroll
        for (int u = 0; u < 4; ++u)
            fh[mm[u] * HSTR + c32] = v[u];             // 2 lanes/bank, free
    }
    __syncthreads();

    // ---- write-out planes 0..34: 70 tasks of one 256B wave-store ----
    for (int i = 0; i < 18; ++i) {
        const int tau = (i << 2) + w;
        if (tau < 70) {
            const int p  = tau >> 1;
            const int sl = ((tau & 1) << 6) + ln;
            const float val = (p < 3) ? xt[p * SLOTS + sl]
                                      : fh[sl * HSTR + (p - 3)];  // 2-way, free
            ob[(size_t)p * plane + sl] = val;
        }
    }
    __syncthreads();

    // ---- stage half 1: channels 32..63 ----
    for (int i = 0; i < 16; i += 4) {
        float v[4];
        int   mm[4];
#pragma unroll
        for (int u = 0; u < 4; ++u) {
            const int m = (w << 5) + ((i + u) << 1) + sub;
            mm[u] = m;
            v[u]  = fb[(size_t)idx_sh[m] * CC + 32 + c32];
        }
#pragma unroll
        for (int u = 0; u < 4; ++u)
            fh[mm[u] * HSTR + c32] = v[u];
    }
    __syncthreads();

    // ---- write-out planes 35..66: exactly 64 tasks ----
    for (int i = 0; i < 16; ++i) {
        const int tau = (i << 2) + w;
        const int pl  = tau >> 1;                       // 0..31
        const int sl  = ((tau & 1) << 6) + ln;
        ob[(size_t)(35 + pl) * plane + sl] = fh[sl * HSTR + pl];
    }
}

extern "C" void kernel_launch(void* const* d_in, const int* in_sizes, int n_in,
                              void* d_out, int out_size, void* d_ws, size_t ws_size,
                              hipStream_t stream) {
    const float* xyz     = (const float*)d_in[0];
    const float* new_xyz = (const float*)d_in[1];
    const float* feat    = (const float*)d_in[2];
    float* out = (float*)d_out;
    (void)d_ws; (void)ws_size;   // idx lives in LDS

    fused_kernel<<<dim3((BB * SS) / QT), dim3(256), 0, stream>>>(xyz, new_xyz, feat, out);
}